// Round 13
// baseline (4860.779 us; speedup 1.0000x reference)
//
#include <hip/hip_runtime.h>
#include <hip/hip_bf16.h>
#include <cstdint>
#include <cstddef>

typedef __bf16 bf16_t;
typedef __bf16 bf16x8 __attribute__((ext_vector_type(8)));
typedef __bf16 bf16x4 __attribute__((ext_vector_type(4)));
typedef float  f32x4  __attribute__((ext_vector_type(4)));

#define M_TOK 12608      // 64*197
#define M_PAD 12800      // 50*256
#define TPADV 224        // vt row length (s-dim padded for K=32 MFMA steps)

// ---------------- helpers ----------------

__device__ __forceinline__ void gload_lds16(const void* g, void* lds) {
  __builtin_amdgcn_global_load_lds(
      (const __attribute__((address_space(1))) void*)g,
      (__attribute__((address_space(3))) void*)lds, 16, 0, 0);
}

__device__ __forceinline__ float wred64(float v) {
  v += __shfl_xor(v, 32); v += __shfl_xor(v, 16); v += __shfl_xor(v, 8);
  v += __shfl_xor(v, 4);  v += __shfl_xor(v, 2);  v += __shfl_xor(v, 1);
  return v;
}

__device__ __forceinline__ float rowred16(float v) {
  v += __shfl_xor(v, 1); v += __shfl_xor(v, 2);
  v += __shfl_xor(v, 4); v += __shfl_xor(v, 8);
  return v;
}

// branch-free erf approx (A&S 7.1.26, |err|<=1.5e-7) for GELU
__device__ __forceinline__ float gelu_fast(float x) {
  const float z = fabsf(x) * 0.70710678118654752f;
  const float t = 1.f / (1.f + 0.3275911f * z);
  const float poly = t * (0.254829592f + t * (-0.284496736f + t * (1.421413741f +
                      t * (-1.453152027f + t * 1.061405429f))));
  const float erfz = 1.f - poly * __expf(-z * z);
  const float erfv = copysignf(erfz, x);
  return 0.5f * x * (1.f + erfv);
}

// ---------------- weight conversion ----------------

// in: [Kd][Nd] fp32 row-major (per blockIdx.z matrix) -> out: [Nd][Kd] bf16
__global__ void tconv_kernel(const float* __restrict__ in, bf16_t* __restrict__ out,
                             int Kd, int Nd) {
  __shared__ float t[32][33];
  const float* ip = in + (size_t)blockIdx.z * Kd * Nd;
  bf16_t* op = out + (size_t)blockIdx.z * Kd * Nd;
  const int n0 = blockIdx.x * 32, k0 = blockIdx.y * 32;
  const int tx = threadIdx.x, ty = threadIdx.y;
#pragma unroll
  for (int r = 0; r < 32; r += 8)
    t[ty + r][tx] = ip[(size_t)(k0 + ty + r) * Nd + n0 + tx];
  __syncthreads();
#pragma unroll
  for (int r = 0; r < 32; r += 8)
    op[(size_t)(n0 + ty + r) * Kd + k0 + tx] = (bf16_t)t[tx][ty + r];
}

// Wq/Wk/Wv: (12,12,768,64) -> Wqkv_t[l]: [2304][768], row n = which*768 + h*64 + d
__global__ void qkvconv_kernel(const float* __restrict__ Wq, const float* __restrict__ Wk,
                               const float* __restrict__ Wv, bf16_t* __restrict__ out) {
  __shared__ float t[32][33];
  const int z = blockIdx.z;
  const int li = z / 36, rem = z % 36, which = rem / 12, hh = rem % 12;
  const float* W = (which == 0) ? Wq : ((which == 1) ? Wk : Wv);
  const float* ip = W + (size_t)(li * 12 + hh) * 768 * 64;
  bf16_t* op = out + (size_t)li * 2304 * 768 + (size_t)(which * 768 + hh * 64) * 768;
  const int k0 = blockIdx.x * 32, d0 = blockIdx.y * 32;
  const int tx = threadIdx.x, ty = threadIdx.y;
#pragma unroll
  for (int r = 0; r < 32; r += 8)
    t[ty + r][tx] = ip[(size_t)(k0 + ty + r) * 64 + d0 + tx];
  __syncthreads();
#pragma unroll
  for (int r = 0; r < 32; r += 8)
    op[(size_t)(d0 + ty + r) * 768 + k0 + tx] = (bf16_t)t[tx][ty + r];
}

// head_w [768][1000] fp32 -> Wht [1024][768] bf16 (rows >=1000 zero)
__global__ void headwconv_kernel(const float* __restrict__ in, bf16_t* __restrict__ out) {
  __shared__ float t[32][33];
  const int n0 = blockIdx.x * 32, k0 = blockIdx.y * 32;
  const int tx = threadIdx.x, ty = threadIdx.y;
#pragma unroll
  for (int r = 0; r < 32; r += 8)
    t[ty + r][tx] = (n0 + tx < 1000) ? in[(size_t)(k0 + ty + r) * 1000 + n0 + tx] : 0.f;
  __syncthreads();
#pragma unroll
  for (int r = 0; r < 32; r += 8)
    out[(size_t)(n0 + ty + r) * 768 + k0 + tx] = (bf16_t)t[tx][ty + r];
}

__global__ void cast_kernel(const float* __restrict__ in, bf16_t* __restrict__ out, int n4) {
  const int id = blockIdx.x * 256 + threadIdx.x;
  if (id >= n4) return;
  float4 v = ((const float4*)in)[id];
  bf16x4 o;
  o[0] = (bf16_t)v.x; o[1] = (bf16_t)v.y; o[2] = (bf16_t)v.z; o[3] = (bf16_t)v.w;
  *(bf16x4*)(out + (size_t)id * 4) = o;
}

// one-time zero of vtb (ensures t in [197,224) pad stays 0; pad is never rewritten)
__global__ void zerovt_kernel(bf16_t* __restrict__ vtb, int n8) {
  bf16x8 z;
#pragma unroll
  for (int k = 0; k < 8; ++k) z[k] = (bf16_t)0.f;
  for (int id = blockIdx.x * 256 + threadIdx.x; id < n8; id += gridDim.x * 256)
    *(bf16x8*)(vtb + (size_t)id * 8) = z;
}

// ---------------- pre/post ----------------

// extract patches: x (64,3,224,224) -> xp [12544][768] bf16, col = c*256+iy*16+ix
__global__ __launch_bounds__(256) void patch_kernel(const float* __restrict__ x,
                                                    bf16_t* __restrict__ xp) {
  const int id = blockIdx.x * 256 + threadIdx.x;   // 12544*48 total
  const int m = id / 48, rem = id % 48;
  const int c = rem >> 4, iy = rem & 15;
  const int pb = m / 196, pp = m - pb * 196;
  const int py = pp / 14, px = pp - py * 14;
  const float4* src = (const float4*)(x + ((size_t)(pb * 3 + c) * 224 + py * 16 + iy) * 224 + px * 16);
  bf16_t* dst = xp + (size_t)m * 768 + c * 256 + iy * 16;
  float4 v0 = src[0], v1 = src[1], v2 = src[2], v3 = src[3];
  bf16x8 o0, o1;
  o0[0] = (bf16_t)v0.x; o0[1] = (bf16_t)v0.y; o0[2] = (bf16_t)v0.z; o0[3] = (bf16_t)v0.w;
  o0[4] = (bf16_t)v1.x; o0[5] = (bf16_t)v1.y; o0[6] = (bf16_t)v1.z; o0[7] = (bf16_t)v1.w;
  o1[0] = (bf16_t)v2.x; o1[1] = (bf16_t)v2.y; o1[2] = (bf16_t)v2.z; o1[3] = (bf16_t)v2.w;
  o1[4] = (bf16_t)v3.x; o1[5] = (bf16_t)v3.y; o1[6] = (bf16_t)v3.z; o1[7] = (bf16_t)v3.w;
  *(bf16x8*)dst = o0;
  *(bf16x8*)(dst + 8) = o1;
}

__global__ void cls_kernel(const float* __restrict__ cls, const float* __restrict__ pos,
                           float* __restrict__ h) {
  const int b = blockIdx.x;
  for (int e = threadIdx.x; e < 768; e += 256)
    h[(size_t)b * 197 * 768 + e] = cls[e] + pos[e];
}

// LayerNorm rows of h (fp32) -> bf16 out
__global__ __launch_bounds__(256) void ln_kernel(const float* __restrict__ h,
    const float* __restrict__ g, const float* __restrict__ bb,
    bf16_t* __restrict__ out, int rows) {
  const int wv = threadIdx.x >> 6, ln = threadIdx.x & 63;
  const int row = blockIdx.x * 4 + wv;
  if (row >= rows) return;
  const float4* hp = (const float4*)(h + (size_t)row * 768);
  float4 xv[3];
  xv[0] = hp[ln]; xv[1] = hp[ln + 64]; xv[2] = hp[ln + 128];
  float s = 0.f;
#pragma unroll
  for (int k = 0; k < 3; ++k) s += xv[k].x + xv[k].y + xv[k].z + xv[k].w;
  s = wred64(s);
  const float mean = s * (1.f / 768.f);
  float vs = 0.f;
#pragma unroll
  for (int k = 0; k < 3; ++k) {
    float a = xv[k].x - mean, b2 = xv[k].y - mean, c = xv[k].z - mean, d = xv[k].w - mean;
    vs += a * a + b2 * b2 + c * c + d * d;
  }
  vs = wred64(vs);
  const float rstd = rsqrtf(vs * (1.f / 768.f) + 1e-5f);
  const float4* gp = (const float4*)g;
  const float4* bp = (const float4*)bb;
  bf16_t* op = out + (size_t)row * 768;
#pragma unroll
  for (int k = 0; k < 3; ++k) {
    const int i4 = ln + 64 * k;
    const float4 gv = gp[i4], bv = bp[i4];
    bf16x4 o;
    o[0] = (bf16_t)((xv[k].x - mean) * rstd * gv.x + bv.x);
    o[1] = (bf16_t)((xv[k].y - mean) * rstd * gv.y + bv.y);
    o[2] = (bf16_t)((xv[k].z - mean) * rstd * gv.z + bv.z);
    o[3] = (bf16_t)((xv[k].w - mean) * rstd * gv.w + bv.w);
    *(bf16x4*)(op + i4 * 4) = o;
  }
}

// final LN on the 64 cls rows -> xcls [256][768] bf16 (rows >=64 zeroed)
__global__ __launch_bounds__(256) void lnf_cls_kernel(const float* __restrict__ h,
    const float* __restrict__ g, const float* __restrict__ bb, bf16_t* __restrict__ out) {
  const int wv = threadIdx.x >> 6, ln = threadIdx.x & 63;
  const int b = blockIdx.x * 4 + wv;   // grid 64 -> b in [0,256)
  bf16_t* op = out + (size_t)b * 768;
  if (b >= 64) {
    bf16x4 z; z[0] = z[1] = z[2] = z[3] = (bf16_t)0.f;
#pragma unroll
    for (int k = 0; k < 3; ++k) *(bf16x4*)(op + (ln + 64 * k) * 4) = z;
    return;
  }
  const float4* hp = (const float4*)(h + (size_t)b * 197 * 768);
  float4 xv[3];
  xv[0] = hp[ln]; xv[1] = hp[ln + 64]; xv[2] = hp[ln + 128];
  float s = 0.f;
#pragma unroll
  for (int k = 0; k < 3; ++k) s += xv[k].x + xv[k].y + xv[k].z + xv[k].w;
  s = wred64(s);
  const float mean = s * (1.f / 768.f);
  float vs = 0.f;
#pragma unroll
  for (int k = 0; k < 3; ++k) {
    float a = xv[k].x - mean, b2 = xv[k].y - mean, c = xv[k].z - mean, d = xv[k].w - mean;
    vs += a * a + b2 * b2 + c * c + d * d;
  }
  vs = wred64(vs);
  const float rstd = rsqrtf(vs * (1.f / 768.f) + 1e-5f);
  const float4* gp = (const float4*)g;
  const float4* bp = (const float4*)bb;
#pragma unroll
  for (int k = 0; k < 3; ++k) {
    const int i4 = ln + 64 * k;
    const float4 gv = gp[i4], bv = bp[i4];
    bf16x4 o;
    o[0] = (bf16_t)((xv[k].x - mean) * rstd * gv.x + bv.x);
    o[1] = (bf16_t)((xv[k].y - mean) * rstd * gv.y + bv.y);
    o[2] = (bf16_t)((xv[k].z - mean) * rstd * gv.z + bv.z);
    o[3] = (bf16_t)((xv[k].w - mean) * rstd * gv.w + bv.w);
    *(bf16x4*)(op + i4 * 4) = o;
  }
}

// ---- GEMM: 256(M)x128(N) tile, BK=32 dbuf (48KB LDS), 8 waves/512thr ----
// Same 2-phase sync template as R9/R12 winner (parameter change only): wave
// (wm=wv>>1 in 0..3, wn=wv&1) owns 64x64. 124 regs -> 4 waves/SIMD -> 2 blocks
// (16 waves/CU vs 12 at the 128x128 tile). T1 XCD chunk remap + T2 swizzle
// (quad q of row r at slot q ^ ((r>>1)&3), pre-swizzled global source).
// EPI_QKV V-blocks: fused V-transpose via dead LDS in TWO 128-row halves
// (tile is 256x128 = 64KB > LDS; each half uses the 32KB Al region).

enum { EPI_PATCH = 0, EPI_QKV = 1, EPI_BIAS_RES = 2, EPI_GELU = 3, EPI_HEAD = 4 };

template <int EPI>
__global__ __launch_bounds__(512, 4)
void gemm256(const bf16_t* __restrict__ A, const bf16_t* __restrict__ Bt,
             int Mvalid, int K, int NT,
             void* __restrict__ out0, const float* __restrict__ bias,
             const float* __restrict__ pos, bf16_t* __restrict__ vtbuf, int ldo) {
  __shared__ __align__(16) bf16_t Al[2][256 * 32];   // 32KB
  __shared__ __align__(16) bf16_t Bl[2][128 * 32];   // 16KB

  // T1: bijective XCD chunk remap (m204)
  const int nwg = gridDim.x;
  const int orig = blockIdx.x;
  const int q8 = nwg >> 3, r8 = nwg & 7;
  const int xcd = orig & 7, idx8 = orig >> 3;
  const int wgid = (xcd < r8 ? xcd * (q8 + 1) : r8 * (q8 + 1) + (xcd - r8) * q8) + idx8;
  const int mt = wgid / NT, nt = wgid - mt * NT;   // nt fast within a chunk

  const int tid = threadIdx.x;
  const int wv = tid >> 6, ln = tid & 63;
  const int wm = wv >> 1, wn = wv & 1;
  const int tl = ln & 15, kg = ln >> 4;
  const int KT = K >> 5;

  // staging: A 256 rows (2 chunks/thread), B 128 rows (1 chunk/thread)
  const int lr = ln >> 2, lq = ln & 3;
  const int la0 = wv * 32 + lr, la1 = la0 + 16;
  const int lb0 = wv * 16 + lr;
  const int ga0 = lq ^ ((la0 >> 1) & 3), ga1 = lq ^ ((la1 >> 1) & 3);
  const int gb0 = lq ^ ((lb0 >> 1) & 3);
  const bf16_t* pA0 = A + (size_t)(mt * 256 + la0) * K + ga0 * 8;
  const bf16_t* pA1 = A + (size_t)(mt * 256 + la1) * K + ga1 * 8;
  const bf16_t* pB0 = Bt + (size_t)(nt * 128 + lb0) * K + gb0 * 8;
  const int cA0 = wv * 1024, cA1 = cA0 + 512;   // elem offsets in A plane
  const int cB0 = wv * 512;                     // elem offset in B plane

#define STAGE(b_, kt_)                                          \
  { gload_lds16(pA0 + (size_t)(kt_) * 32, &Al[b_][cA0]);        \
    gload_lds16(pA1 + (size_t)(kt_) * 32, &Al[b_][cA1]);        \
    gload_lds16(pB0 + (size_t)(kt_) * 32, &Bl[b_][cB0]); }

  f32x4 acc[4][4];
#pragma unroll
  for (int i = 0; i < 4; ++i)
#pragma unroll
    for (int j = 0; j < 4; ++j) {
      acc[i][j][0] = 0.f; acc[i][j][1] = 0.f; acc[i][j][2] = 0.f; acc[i][j][3] = 0.f;
    }

  STAGE(0, 0);
  __syncthreads();
  for (int kt = 0; kt < KT; ++kt) {
    const int buf = kt & 1;
    if (kt + 1 < KT) STAGE(buf ^ 1, kt + 1);
    bf16x8 af[4], bfr[4];
#pragma unroll
    for (int i = 0; i < 4; ++i) {
      const int ra = wm * 64 + i * 16 + tl;           // 0..255
      af[i] = *(const bf16x8*)(((const char*)&Al[buf][0]) + ra * 64 +
                               (((kg ^ (ra >> 1)) & 3) << 4));
    }
#pragma unroll
    for (int j = 0; j < 4; ++j) {
      const int rb = wn * 64 + j * 16 + tl;           // 0..127
      bfr[j] = *(const bf16x8*)(((const char*)&Bl[buf][0]) + rb * 64 +
                                (((kg ^ (rb >> 1)) & 3) << 4));
    }
    __builtin_amdgcn_s_setprio(1);
#pragma unroll
    for (int i = 0; i < 4; ++i)
#pragma unroll
      for (int j = 0; j < 4; ++j)
        acc[i][j] = __builtin_amdgcn_mfma_f32_16x16x32_bf16(af[i], bfr[j], acc[i][j], 0, 0, 0);
    __builtin_amdgcn_s_setprio(0);
    __syncthreads();
  }
#undef STAGE

  const int mb = mt * 256 + wm * 64, nb = nt * 128 + wn * 64;

  if constexpr (EPI == EPI_QKV) {
    if (nt >= 12) {
      // ---- fused V transpose via dead LDS, two 128-row halves ----
      char* Tl = (char*)&Al[0][0];                 // 32KB = [128m][128d] swizzled
      const int dblk = nt * 128 - 1536;
#pragma unroll
      for (int h = 0; h < 2; ++h) {
        if ((wm >> 1) == h) {
#pragma unroll
          for (int i = 0; i < 4; ++i)
#pragma unroll
            for (int j = 0; j < 4; ++j)
#pragma unroll
              for (int r = 0; r < 4; ++r) {
                const int m_l = (wm & 1) * 64 + i * 16 + kg * 4 + r;   // 0..127
                const int d_l = wn * 64 + j * 16 + tl;
                const int quad = (d_l >> 3) ^ (m_l & 15) ^ ((m_l >> 4) & 3);
                *(bf16_t*)(Tl + m_l * 256 + quad * 16 + (d_l & 7) * 2) =
                    (bf16_t)acc[i][j][r];
              }
        }
        __syncthreads();
#pragma unroll
        for (int e4 = 0; e4 < 32; ++e4) {
          const int e = e4 * 512 + tid;
          const int m_l = e & 127, d_l = e >> 7;
          const int m = mt * 256 + h * 128 + m_l;
          if (m < Mvalid) {
            const int quad = (d_l >> 3) ^ (m_l & 15) ^ ((m_l >> 4) & 3);
            const bf16_t val = *(const bf16_t*)(Tl + m_l * 256 + quad * 16 + (d_l & 7) * 2);
            const int dv = dblk + d_l;
            const int pb = m / 197, tt = m - pb * 197;
            vtbuf[((size_t)(pb * 12 + (dv >> 6)) * 64 + (dv & 63)) * TPADV + tt] = val;
          }
        }
        __syncthreads();
      }
      return;
    }
    // Q/K blocks fall through to the standard epilogue
  }

#pragma unroll
  for (int i = 0; i < 4; ++i) {
#pragma unroll
    for (int j = 0; j < 4; ++j) {
#pragma unroll
      for (int r = 0; r < 4; ++r) {
        const int m = mb + i * 16 + kg * 4 + r;
        const int n = nb + j * 16 + tl;
        if (m >= Mvalid) continue;
        const float v = acc[i][j][r];
        if constexpr (EPI == EPI_PATCH) {
          const int pb = m / 196, pp = m - pb * 196;
          const float val = v + bias[n] + pos[(size_t)(pp + 1) * 768 + n];
          ((float*)out0)[(size_t)(m + pb + 1) * 768 + n] = val;
        } else if constexpr (EPI == EPI_QKV) {
          ((bf16_t*)out0)[(size_t)m * 1536 + n] = (bf16_t)v;
        } else if constexpr (EPI == EPI_BIAS_RES) {
          float* hp = (float*)out0 + (size_t)m * 768 + n;
          *hp += v + bias[n];
        } else if constexpr (EPI == EPI_HEAD) {
          if (n < 1000)
            ((float*)out0)[(size_t)m * 1000 + n] = v + bias[n];
        } else {  // EPI_GELU
          ((bf16_t*)out0)[(size_t)m * (size_t)ldo + n] = (bf16_t)gelu_fast(v + bias[n]);
        }
      }
    }
  }
}

// ---------------- attention ----------------
// qk: [M_PAD][1536] bf16 (q cols 0..767 = h*64+d, k cols 768..1535)
// vt: [768][64][TPADV] bf16  (per (b*12+h): V^T, row d, col t; t>=197 zeroed once)
// attno: [M_PAD][768] bf16
__global__ __launch_bounds__(256, 2)
void attn_kernel(const bf16_t* __restrict__ qk, const bf16_t* __restrict__ vt,
                 bf16_t* __restrict__ attno) {
  __shared__ bf16_t Kl[224 * 72];
  __shared__ bf16_t Pl[4][16 * 232];
  const int bh = blockIdx.x;
  const int b = bh / 12, hh = bh % 12;
  const int tid = threadIdx.x, wv = tid >> 6, ln = tid & 63;
  const int tl = ln & 15, kg = ln >> 4;

  for (int idx = tid; idx < 224 * 8; idx += 256) {
    const int s = idx >> 3, c = idx & 7;
    bf16x8 val;
    if (s < 197) {
      val = *(const bf16x8*)(qk + (size_t)(b * 197 + s) * 1536 + 768 + hh * 64 + c * 8);
    } else {
#pragma unroll
      for (int j2 = 0; j2 < 8; ++j2) val[j2] = (bf16_t)0.f;
    }
    *(bf16x8*)&Kl[s * 72 + c * 8] = val;
  }
  __syncthreads();

  for (int qt = wv; qt < 13; qt += 4) {
    const size_t qoff = (size_t)(b * 197 + qt * 16 + tl) * 1536 + hh * 64 + kg * 8;
    const bf16x8 aq0 = *(const bf16x8*)(qk + qoff);
    const bf16x8 aq1 = *(const bf16x8*)(qk + qoff + 32);
    f32x4 sc[13];
#pragma unroll
    for (int st = 0; st < 13; ++st) {
      const bf16x8 bk0 = *(const bf16x8*)&Kl[(st * 16 + tl) * 72 + kg * 8];
      const bf16x8 bk1 = *(const bf16x8*)&Kl[(st * 16 + tl) * 72 + 32 + kg * 8];
      f32x4 z = {0.f, 0.f, 0.f, 0.f};
      z = __builtin_amdgcn_mfma_f32_16x16x32_bf16(aq0, bk0, z, 0, 0, 0);
      z = __builtin_amdgcn_mfma_f32_16x16x32_bf16(aq1, bk1, z, 0, 0, 0);
      sc[st] = z;
    }
#pragma unroll
    for (int st = 0; st < 13; ++st)
#pragma unroll
      for (int r = 0; r < 4; ++r) sc[st][r] *= 0.125f;  // HS^-0.5

    float inv[4];
#pragma unroll
    for (int r = 0; r < 4; ++r) {
      float sum = 0.f;
#pragma unroll
      for (int st = 0; st < 13; ++st)
        if (st * 16 + tl < 197) sum += sc[st][r];
      sum = rowred16(sum);
      const float mean = sum * (1.f / 197.f);
      float ss = 0.f;
#pragma unroll
      for (int st = 0; st < 13; ++st)
        if (st * 16 + tl < 197) { const float cc = sc[st][r] - mean; ss += cc * cc; }
      ss = rowred16(ss);
      const float rstd = rsqrtf(ss * (1.f / 197.f) + 1e-5f);
      float ps = 0.f;
#pragma unroll
      for (int st = 0; st < 13; ++st) {
        const int s = st * 16 + tl;
        float p = 0.f;
        if (s < 197) p = __expf((sc[st][r] - mean) * rstd);
        ps += p;
        Pl[wv][(kg * 4 + r) * 232 + st * 16 + tl] = (bf16_t)p;
      }
      ps = rowred16(ps);
      inv[r] = 1.f / ps;
      Pl[wv][(kg * 4 + r) * 232 + 208 + tl] = (bf16_t)0.f;
      if (tl < 8) Pl[wv][(kg * 4 + r) * 232 + 224 + tl] = (bf16_t)0.f;
    }

    f32x4 oa[4];
#pragma unroll
    for (int nf = 0; nf < 4; ++nf) {
      oa[nf][0] = 0.f; oa[nf][1] = 0.f; oa[nf][2] = 0.f; oa[nf][3] = 0.f;
    }
#pragma unroll
    for (int kk = 0; kk < 7; ++kk) {
      const bf16x8 pa = *(const bf16x8*)&Pl[wv][tl * 232 + kk * 32 + kg * 8];
#pragma unroll
      for (int nf = 0; nf < 4; ++nf) {
        const bf16x8 vb = *(const bf16x8*)(vt + ((size_t)bh * 64 + nf * 16 + tl) * TPADV + kk * 32 + kg * 8);
        oa[nf] = __builtin_amdgcn_mfma_f32_16x16x32_bf16(pa, vb, oa[nf], 0, 0, 0);
      }
    }
#pragma unroll
    for (int nf = 0; nf < 4; ++nf)
#pragma unroll
      for (int r = 0; r < 4; ++r) {
        const int t = qt * 16 + kg * 4 + r;
        if (t < 197)
          attno[(size_t)(b * 197 + t) * 768 + hh * 64 + nf * 16 + tl] =
              (bf16_t)(oa[nf][r] * inv[r]);
      }
  }
}

// ---------------- launch ----------------

extern "C" void kernel_launch(void* const* d_in, const int* in_sizes, int n_in,
                              void* d_out, int out_size, void* d_ws, size_t ws_size,
                              hipStream_t stream) {
  (void)in_sizes; (void)n_in; (void)out_size; (void)ws_size;
  const float* x      = (const float*)d_in[0];
  const float* conv_w = (const float*)d_in[1];
  const float* conv_b = (const float*)d_in[2];
  const float* cls_t  = (const float*)d_in[3];
  const float* pos    = (const float*)d_in[4];
  const float* Wq     = (const float*)d_in[5];
  const float* Wk     = (const float*)d_in[6];
  const float* Wv     = (const float*)d_in[7];
  const float* proj_w = (const float*)d_in[8];
  const float* proj_b = (const float*)d_in[9];
  const float* ln1_g  = (const float*)d_in[10];
  const float* ln1_b  = (const float*)d_in[11];
  const float* ln2_g  = (const float*)d_in[12];
  const float* ln2_b  = (const float*)d_in[13];
  const float* ff1_w  = (const float*)d_in[14];
  const float* ff1_b  = (const float*)d_in[15];
  const float* ff2_w  = (const float*)d_in[16];
  const float* ff2_b  = (const float*)d_in[17];
  const float* lnf_g  = (const float*)d_in[18];
  const float* lnf_b  = (const float*)d_in[19];
  const float* head_w = (const float*)d_in[20];
  const float* head_b = (const float*)d_in[21];
  float* out = (float*)d_out;

  char* w = (char*)d_ws;
  size_t off = 0;
  auto take = [&](size_t bytes) {
    char* p = w + off;
    off = (off + bytes + 255) & ~(size_t)255;
    return p;
  };
  bf16_t* Wc_t    = (bf16_t*)take((size_t)768 * 768 * 2);
  bf16_t* Wqkv_t  = (bf16_t*)take((size_t)12 * 2304 * 768 * 2);
  bf16_t* Wproj_t = (bf16_t*)take((size_t)12 * 768 * 768 * 2);
  bf16_t* Wff1_t  = (bf16_t*)take((size_t)12 * 3072 * 768 * 2);
  bf16_t* Wff2_t  = (bf16_t*)take((size_t)12 * 768 * 3072 * 2);
  bf16_t* Wht     = (bf16_t*)take((size_t)1024 * 768 * 2);
  float*  hbuf    = (float*)take((size_t)M_PAD * 768 * 4);
  bf16_t* xn      = (bf16_t*)take((size_t)M_PAD * 768 * 2);
  bf16_t* qkb     = (bf16_t*)take((size_t)M_PAD * 1536 * 2);
  bf16_t* vtb     = (bf16_t*)take((size_t)768 * 64 * TPADV * 2);
  bf16_t* attno   = (bf16_t*)take((size_t)M_PAD * 768 * 2);
  bf16_t* ffa     = (bf16_t*)take((size_t)M_PAD * 3072 * 2);
  bf16_t* xcls    = (bf16_t*)take((size_t)256 * 768 * 2);

  const dim3 blk256(256);
  const dim3 blk512(512);
  const dim3 tb(32, 8);

  // weight conversion (fp32 -> bf16, [N][K] transposed layouts)
  tconv_kernel<<<dim3(24, 24, 12), tb, 0, stream>>>(proj_w, Wproj_t, 768, 768);
  tconv_kernel<<<dim3(96, 24, 12), tb, 0, stream>>>(ff1_w, Wff1_t, 768, 3072);
  tconv_kernel<<<dim3(24, 96, 12), tb, 0, stream>>>(ff2_w, Wff2_t, 3072, 768);
  qkvconv_kernel<<<dim3(24, 2, 432), tb, 0, stream>>>(Wq, Wk, Wv, Wqkv_t);
  headwconv_kernel<<<dim3(32, 24), tb, 0, stream>>>(head_w, Wht);
  cast_kernel<<<dim3(576), blk256, 0, stream>>>(conv_w, Wc_t, 147456);
  zerovt_kernel<<<dim3(2048), blk256, 0, stream>>>(vtb, 768 * 64 * TPADV / 8);

  // patch embed (12544 = 49*256 exactly)
  patch_kernel<<<dim3(2352), blk256, 0, stream>>>(x, xn);
  cls_kernel<<<dim3(64), blk256, 0, stream>>>(cls_t, pos, hbuf);
  gemm256<EPI_PATCH><<<dim3(49 * 6), blk512, 0, stream>>>(
      xn, Wc_t, 12544, 768, 6, (void*)hbuf, conv_b, pos, (bf16_t*)nullptr, 768);

  for (int i = 0; i < 12; ++i) {
    ln_kernel<<<dim3(3152), blk256, 0, stream>>>(hbuf, ln1_g + i * 768, ln1_b + i * 768, xn, M_TOK);
    // QKV: q,k -> qkb coalesced; V -> vtb via fused in-LDS transpose
    gemm256<EPI_QKV><<<dim3(50 * 18), blk512, 0, stream>>>(
        xn, Wqkv_t + (size_t)i * 2304 * 768, M_TOK, 768, 18, (void*)qkb,
        (const float*)nullptr, (const float*)nullptr, vtb, 1536);
    attn_kernel<<<dim3(768), blk256, 0, stream>>>(qkb, vtb, attno);
    gemm256<EPI_BIAS_RES><<<dim3(50 * 6), blk512, 0, stream>>>(
        attno, Wproj_t + (size_t)i * 768 * 768, M_TOK, 768, 6, (void*)hbuf,
        proj_b + i * 768, (const float*)nullptr, (bf16_t*)nullptr, 768);
    ln_kernel<<<dim3(3152), blk256, 0, stream>>>(hbuf, ln2_g + i * 768, ln2_b + i * 768, xn, M_TOK);
    gemm256<EPI_GELU><<<dim3(50 * 24), blk512, 0, stream>>>(
        xn, Wff1_t + (size_t)i * 768 * 3072, M_TOK, 768, 24, (void*)ffa,
        ff1_b + i * 3072, (const float*)nullptr, (bf16_t*)nullptr, 3072);
    gemm256<EPI_BIAS_RES><<<dim3(50 * 6), blk512, 0, stream>>>(
        ffa, Wff2_t + (size_t)i * 3072 * 768, M_TOK, 3072, 6, (void*)hbuf,
        ff2_b + i * 768, (const float*)nullptr, (bf16_t*)nullptr, 768);
  }

  lnf_cls_kernel<<<dim3(64), blk256, 0, stream>>>(hbuf, lnf_g, lnf_b, xcls);
  gemm256<EPI_HEAD><<<dim3(8), blk512, 0, stream>>>(
      xcls, Wht, 64, 768, 8, (void*)out, head_b, (const float*)nullptr,
      (bf16_t*)nullptr, 1000);
}

// Round 14
// 4666.431 us; speedup vs baseline: 1.0416x; 1.0416x over previous
//
#include <hip/hip_runtime.h>
#include <hip/hip_bf16.h>
#include <cstdint>
#include <cstddef>

typedef __bf16 bf16_t;
typedef __bf16 bf16x8 __attribute__((ext_vector_type(8)));
typedef __bf16 bf16x4 __attribute__((ext_vector_type(4)));
typedef float  f32x4  __attribute__((ext_vector_type(4)));

#define M_TOK 12608      // 64*197
#define M_PAD 12672      // 99*128
#define TPADV 224        // vt row length (s-dim padded for K=32 MFMA steps)

// ---------------- helpers ----------------

__device__ __forceinline__ void gload_lds16(const void* g, void* lds) {
  __builtin_amdgcn_global_load_lds(
      (const __attribute__((address_space(1))) void*)g,
      (__attribute__((address_space(3))) void*)lds, 16, 0, 0);
}

__device__ __forceinline__ float wred64(float v) {
  v += __shfl_xor(v, 32); v += __shfl_xor(v, 16); v += __shfl_xor(v, 8);
  v += __shfl_xor(v, 4);  v += __shfl_xor(v, 2);  v += __shfl_xor(v, 1);
  return v;
}

__device__ __forceinline__ float rowred16(float v) {
  v += __shfl_xor(v, 1); v += __shfl_xor(v, 2);
  v += __shfl_xor(v, 4); v += __shfl_xor(v, 8);
  return v;
}

// branch-free erf approx (A&S 7.1.26, |err|<=1.5e-7) for GELU
__device__ __forceinline__ float gelu_fast(float x) {
  const float z = fabsf(x) * 0.70710678118654752f;
  const float t = 1.f / (1.f + 0.3275911f * z);
  const float poly = t * (0.254829592f + t * (-0.284496736f + t * (1.421413741f +
                      t * (-1.453152027f + t * 1.061405429f))));
  const float erfz = 1.f - poly * __expf(-z * z);
  const float erfv = copysignf(erfz, x);
  return 0.5f * x * (1.f + erfv);
}

// ---------------- weight conversion ----------------

// in: [Kd][Nd] fp32 row-major (per blockIdx.z matrix) -> out: [Nd][Kd] bf16
__global__ void tconv_kernel(const float* __restrict__ in, bf16_t* __restrict__ out,
                             int Kd, int Nd) {
  __shared__ float t[32][33];
  const float* ip = in + (size_t)blockIdx.z * Kd * Nd;
  bf16_t* op = out + (size_t)blockIdx.z * Kd * Nd;
  const int n0 = blockIdx.x * 32, k0 = blockIdx.y * 32;
  const int tx = threadIdx.x, ty = threadIdx.y;
#pragma unroll
  for (int r = 0; r < 32; r += 8)
    t[ty + r][tx] = ip[(size_t)(k0 + ty + r) * Nd + n0 + tx];
  __syncthreads();
#pragma unroll
  for (int r = 0; r < 32; r += 8)
    op[(size_t)(n0 + ty + r) * Kd + k0 + tx] = (bf16_t)t[tx][ty + r];
}

// Wq/Wk/Wv: (12,12,768,64) -> Wqkv_t[l]: [2304][768], row n = which*768 + h*64 + d
__global__ void qkvconv_kernel(const float* __restrict__ Wq, const float* __restrict__ Wk,
                               const float* __restrict__ Wv, bf16_t* __restrict__ out) {
  __shared__ float t[32][33];
  const int z = blockIdx.z;
  const int li = z / 36, rem = z % 36, which = rem / 12, hh = rem % 12;
  const float* W = (which == 0) ? Wq : ((which == 1) ? Wk : Wv);
  const float* ip = W + (size_t)(li * 12 + hh) * 768 * 64;
  bf16_t* op = out + (size_t)li * 2304 * 768 + (size_t)(which * 768 + hh * 64) * 768;
  const int k0 = blockIdx.x * 32, d0 = blockIdx.y * 32;
  const int tx = threadIdx.x, ty = threadIdx.y;
#pragma unroll
  for (int r = 0; r < 32; r += 8)
    t[ty + r][tx] = ip[(size_t)(k0 + ty + r) * 64 + d0 + tx];
  __syncthreads();
#pragma unroll
  for (int r = 0; r < 32; r += 8)
    op[(size_t)(d0 + ty + r) * 768 + k0 + tx] = (bf16_t)t[tx][ty + r];
}

// head_w [768][1000] fp32 -> Wht [1024][768] bf16 (rows >=1000 zero)
__global__ void headwconv_kernel(const float* __restrict__ in, bf16_t* __restrict__ out) {
  __shared__ float t[32][33];
  const int n0 = blockIdx.x * 32, k0 = blockIdx.y * 32;
  const int tx = threadIdx.x, ty = threadIdx.y;
#pragma unroll
  for (int r = 0; r < 32; r += 8)
    t[ty + r][tx] = (n0 + tx < 1000) ? in[(size_t)(k0 + ty + r) * 1000 + n0 + tx] : 0.f;
  __syncthreads();
#pragma unroll
  for (int r = 0; r < 32; r += 8)
    out[(size_t)(n0 + ty + r) * 768 + k0 + tx] = (bf16_t)t[tx][ty + r];
}

__global__ void cast_kernel(const float* __restrict__ in, bf16_t* __restrict__ out, int n4) {
  const int id = blockIdx.x * 256 + threadIdx.x;
  if (id >= n4) return;
  float4 v = ((const float4*)in)[id];
  bf16x4 o;
  o[0] = (bf16_t)v.x; o[1] = (bf16_t)v.y; o[2] = (bf16_t)v.z; o[3] = (bf16_t)v.w;
  *(bf16x4*)(out + (size_t)id * 4) = o;
}

// one-time zero of vtb (ensures t in [197,224) pad stays 0; pad is never rewritten)
__global__ void zerovt_kernel(bf16_t* __restrict__ vtb, int n8) {
  bf16x8 z;
#pragma unroll
  for (int k = 0; k < 8; ++k) z[k] = (bf16_t)0.f;
  for (int id = blockIdx.x * 256 + threadIdx.x; id < n8; id += gridDim.x * 256)
    *(bf16x8*)(vtb + (size_t)id * 8) = z;
}

// ---------------- pre/post ----------------

// extract patches: x (64,3,224,224) -> xp [12544][768] bf16, col = c*256+iy*16+ix
__global__ __launch_bounds__(256) void patch_kernel(const float* __restrict__ x,
                                                    bf16_t* __restrict__ xp) {
  const int id = blockIdx.x * 256 + threadIdx.x;   // 12544*48 total
  const int m = id / 48, rem = id % 48;
  const int c = rem >> 4, iy = rem & 15;
  const int pb = m / 196, pp = m - pb * 196;
  const int py = pp / 14, px = pp - py * 14;
  const float4* src = (const float4*)(x + ((size_t)(pb * 3 + c) * 224 + py * 16 + iy) * 224 + px * 16);
  bf16_t* dst = xp + (size_t)m * 768 + c * 256 + iy * 16;
  float4 v0 = src[0], v1 = src[1], v2 = src[2], v3 = src[3];
  bf16x8 o0, o1;
  o0[0] = (bf16_t)v0.x; o0[1] = (bf16_t)v0.y; o0[2] = (bf16_t)v0.z; o0[3] = (bf16_t)v0.w;
  o0[4] = (bf16_t)v1.x; o0[5] = (bf16_t)v1.y; o0[6] = (bf16_t)v1.z; o0[7] = (bf16_t)v1.w;
  o1[0] = (bf16_t)v2.x; o1[1] = (bf16_t)v2.y; o1[2] = (bf16_t)v2.z; o1[3] = (bf16_t)v2.w;
  o1[4] = (bf16_t)v3.x; o1[5] = (bf16_t)v3.y; o1[6] = (bf16_t)v3.z; o1[7] = (bf16_t)v3.w;
  *(bf16x8*)dst = o0;
  *(bf16x8*)(dst + 8) = o1;
}

__global__ void cls_kernel(const float* __restrict__ cls, const float* __restrict__ pos,
                           float* __restrict__ h) {
  const int b = blockIdx.x;
  for (int e = threadIdx.x; e < 768; e += 256)
    h[(size_t)b * 197 * 768 + e] = cls[e] + pos[e];
}

// LayerNorm rows of h (fp32) -> bf16 out
__global__ __launch_bounds__(256) void ln_kernel(const float* __restrict__ h,
    const float* __restrict__ g, const float* __restrict__ bb,
    bf16_t* __restrict__ out, int rows) {
  const int wv = threadIdx.x >> 6, ln = threadIdx.x & 63;
  const int row = blockIdx.x * 4 + wv;
  if (row >= rows) return;
  const float4* hp = (const float4*)(h + (size_t)row * 768);
  float4 xv[3];
  xv[0] = hp[ln]; xv[1] = hp[ln + 64]; xv[2] = hp[ln + 128];
  float s = 0.f;
#pragma unroll
  for (int k = 0; k < 3; ++k) s += xv[k].x + xv[k].y + xv[k].z + xv[k].w;
  s = wred64(s);
  const float mean = s * (1.f / 768.f);
  float vs = 0.f;
#pragma unroll
  for (int k = 0; k < 3; ++k) {
    float a = xv[k].x - mean, b2 = xv[k].y - mean, c = xv[k].z - mean, d = xv[k].w - mean;
    vs += a * a + b2 * b2 + c * c + d * d;
  }
  vs = wred64(vs);
  const float rstd = rsqrtf(vs * (1.f / 768.f) + 1e-5f);
  const float4* gp = (const float4*)g;
  const float4* bp = (const float4*)bb;
  bf16_t* op = out + (size_t)row * 768;
#pragma unroll
  for (int k = 0; k < 3; ++k) {
    const int i4 = ln + 64 * k;
    const float4 gv = gp[i4], bv = bp[i4];
    bf16x4 o;
    o[0] = (bf16_t)((xv[k].x - mean) * rstd * gv.x + bv.x);
    o[1] = (bf16_t)((xv[k].y - mean) * rstd * gv.y + bv.y);
    o[2] = (bf16_t)((xv[k].z - mean) * rstd * gv.z + bv.z);
    o[3] = (bf16_t)((xv[k].w - mean) * rstd * gv.w + bv.w);
    *(bf16x4*)(op + i4 * 4) = o;
  }
}

// final LN on the 64 cls rows -> xcls [256][768] bf16 (rows >=64 zeroed)
__global__ __launch_bounds__(256) void lnf_cls_kernel(const float* __restrict__ h,
    const float* __restrict__ g, const float* __restrict__ bb, bf16_t* __restrict__ out) {
  const int wv = threadIdx.x >> 6, ln = threadIdx.x & 63;
  const int b = blockIdx.x * 4 + wv;   // grid 64 -> b in [0,256)
  bf16_t* op = out + (size_t)b * 768;
  if (b >= 64) {
    bf16x4 z; z[0] = z[1] = z[2] = z[3] = (bf16_t)0.f;
#pragma unroll
    for (int k = 0; k < 3; ++k) *(bf16x4*)(op + (ln + 64 * k) * 4) = z;
    return;
  }
  const float4* hp = (const float4*)(h + (size_t)b * 197 * 768);
  float4 xv[3];
  xv[0] = hp[ln]; xv[1] = hp[ln + 64]; xv[2] = hp[ln + 128];
  float s = 0.f;
#pragma unroll
  for (int k = 0; k < 3; ++k) s += xv[k].x + xv[k].y + xv[k].z + xv[k].w;
  s = wred64(s);
  const float mean = s * (1.f / 768.f);
  float vs = 0.f;
#pragma unroll
  for (int k = 0; k < 3; ++k) {
    float a = xv[k].x - mean, b2 = xv[k].y - mean, c = xv[k].z - mean, d = xv[k].w - mean;
    vs += a * a + b2 * b2 + c * c + d * d;
  }
  vs = wred64(vs);
  const float rstd = rsqrtf(vs * (1.f / 768.f) + 1e-5f);
  const float4* gp = (const float4*)g;
  const float4* bp = (const float4*)bb;
#pragma unroll
  for (int k = 0; k < 3; ++k) {
    const int i4 = ln + 64 * k;
    const float4 gv = gp[i4], bv = bp[i4];
    bf16x4 o;
    o[0] = (bf16_t)((xv[k].x - mean) * rstd * gv.x + bv.x);
    o[1] = (bf16_t)((xv[k].y - mean) * rstd * gv.y + bv.y);
    o[2] = (bf16_t)((xv[k].z - mean) * rstd * gv.z + bv.z);
    o[3] = (bf16_t)((xv[k].w - mean) * rstd * gv.w + bv.w);
    *(bf16x4*)(op + i4 * 4) = o;
  }
}

// ---- GEMM: 128x128 tile, BK=32 dbuf (32KB LDS), 4 waves, T2 swizzle, T1 XCD chunk ----
// Round-12 winner (verified 4681us). EPI_QKV V-blocks (nt>=12) fuse the V-transpose:
// after the K-loop, the dead 32KB LDS is reused as a [128m][128d] tile with quad
// swizzle (d>>3)^(m&15)^((m>>4)&3) (same formula store+read), then written
// transposed to vtb with consecutive-m lanes (coalesced).

enum { EPI_PATCH = 0, EPI_QKV = 1, EPI_BIAS_RES = 2, EPI_GELU = 3, EPI_HEAD = 4 };

template <int EPI>
__global__ __launch_bounds__(256, 4)
void gemm128(const bf16_t* __restrict__ A, const bf16_t* __restrict__ Bt,
             int Mvalid, int K, int NT,
             void* __restrict__ out0, const float* __restrict__ bias,
             const float* __restrict__ pos, bf16_t* __restrict__ vtbuf, int ldo) {
  __shared__ __align__(16) bf16_t LdsAll[2][2][128 * 32];   // [A/B][dbuf][plane]

  // T1: bijective XCD chunk remap (m204). orig%8 = XCD; chunk = contiguous wgid range.
  const int nwg = gridDim.x;
  const int orig = blockIdx.x;
  const int q8 = nwg >> 3, r8 = nwg & 7;
  const int xcd = orig & 7, idx8 = orig >> 3;
  const int wgid = (xcd < r8 ? xcd * (q8 + 1) : r8 * (q8 + 1) + (xcd - r8) * q8) + idx8;
  const int mt = wgid / NT, nt = wgid - mt * NT;   // nt fast within a chunk

  const int tid = threadIdx.x;
  const int wv = tid >> 6, ln = tid & 63;
  const int wm = wv >> 1, wn = wv & 1;
  const int tl = ln & 15, kg = ln >> 4;
  const int KT = K >> 5;

  // staging: 256 threads cover 128 rows x 32 k for A and B (2 chunks each)
  const int lr = ln >> 2, lq = ln & 3;
  const int la0 = wv * 32 + lr, la1 = wv * 32 + 16 + lr;   // tile-local rows
  const int ga0 = lq ^ ((la0 >> 1) & 3), ga1 = lq ^ ((la1 >> 1) & 3);
  const bf16_t* pA0 = A + (size_t)(mt * 128 + la0) * K + ga0 * 8;
  const bf16_t* pA1 = A + (size_t)(mt * 128 + la1) * K + ga1 * 8;
  const bf16_t* pB0 = Bt + (size_t)(nt * 128 + la0) * K + ga0 * 8;
  const bf16_t* pB1 = Bt + (size_t)(nt * 128 + la1) * K + ga1 * 8;
  const int c0 = wv * 1024, c1 = wv * 1024 + 512;

#define STAGE(b_, kt_)                                               \
  { gload_lds16(pA0 + (size_t)(kt_) * 32, &LdsAll[0][b_][c0]);       \
    gload_lds16(pA1 + (size_t)(kt_) * 32, &LdsAll[0][b_][c1]);       \
    gload_lds16(pB0 + (size_t)(kt_) * 32, &LdsAll[1][b_][c0]);       \
    gload_lds16(pB1 + (size_t)(kt_) * 32, &LdsAll[1][b_][c1]); }

  f32x4 acc[4][4];
#pragma unroll
  for (int i = 0; i < 4; ++i)
#pragma unroll
    for (int j = 0; j < 4; ++j) {
      acc[i][j][0] = 0.f; acc[i][j][1] = 0.f; acc[i][j][2] = 0.f; acc[i][j][3] = 0.f;
    }

  STAGE(0, 0);
  __syncthreads();
  for (int kt = 0; kt < KT; ++kt) {
    const int buf = kt & 1;
    if (kt + 1 < KT) STAGE(buf ^ 1, kt + 1);
    bf16x8 af[4], bfr[4];
#pragma unroll
    for (int i = 0; i < 4; ++i) {
      const int ra = wm * 64 + i * 16 + tl;
      af[i] = *(const bf16x8*)(((const char*)&LdsAll[0][buf][0]) + ra * 64 +
                               (((kg ^ (ra >> 1)) & 3) << 4));
    }
#pragma unroll
    for (int j = 0; j < 4; ++j) {
      const int rb = wn * 64 + j * 16 + tl;
      bfr[j] = *(const bf16x8*)(((const char*)&LdsAll[1][buf][0]) + rb * 64 +
                                (((kg ^ (rb >> 1)) & 3) << 4));
    }
    __builtin_amdgcn_s_setprio(1);
#pragma unroll
    for (int i = 0; i < 4; ++i)
#pragma unroll
      for (int j = 0; j < 4; ++j)
        acc[i][j] = __builtin_amdgcn_mfma_f32_16x16x32_bf16(af[i], bfr[j], acc[i][j], 0, 0, 0);
    __builtin_amdgcn_s_setprio(0);
    __syncthreads();
  }
#undef STAGE

  const int mb = mt * 128 + wm * 64, nb = nt * 128 + wn * 64;

  if constexpr (EPI == EPI_QKV) {
    if (nt >= 12) {
      // ---- fused V transpose via dead LDS (32KB = [128m][128d] bf16, quad-swizzled) ----
      char* Tl = (char*)&LdsAll[0][0][0];
      const int dblk = nt * 128 - 1536;              // block's V-col base
#pragma unroll
      for (int i = 0; i < 4; ++i)
#pragma unroll
        for (int j = 0; j < 4; ++j)
#pragma unroll
          for (int r = 0; r < 4; ++r) {
            const int m_l = wm * 64 + i * 16 + kg * 4 + r;
            const int d_l = wn * 64 + j * 16 + tl;
            const int quad = (d_l >> 3) ^ (m_l & 15) ^ ((m_l >> 4) & 3);
            *(bf16_t*)(Tl + m_l * 256 + quad * 16 + (d_l & 7) * 2) = (bf16_t)acc[i][j][r];
          }
      __syncthreads();
      const int mB = mt * 128;
#pragma unroll
      for (int e4 = 0; e4 < 64; ++e4) {
        const int e = e4 * 256 + tid;
        const int m_l = e & 127, d_l = e >> 7;
        const int m = mB + m_l;
        if (m < Mvalid) {
          const int quad = (d_l >> 3) ^ (m_l & 15) ^ ((m_l >> 4) & 3);
          const bf16_t val = *(const bf16_t*)(Tl + m_l * 256 + quad * 16 + (d_l & 7) * 2);
          const int dv = dblk + d_l;
          const int pb = m / 197, tt = m - pb * 197;
          vtbuf[((size_t)(pb * 12 + (dv >> 6)) * 64 + (dv & 63)) * TPADV + tt] = val;
        }
      }
      return;
    }
    // Q/K blocks fall through to the standard epilogue
  }

#pragma unroll
  for (int i = 0; i < 4; ++i) {
#pragma unroll
    for (int j = 0; j < 4; ++j) {
#pragma unroll
      for (int r = 0; r < 4; ++r) {
        const int m = mb + i * 16 + kg * 4 + r;
        const int n = nb + j * 16 + tl;
        if (m >= Mvalid) continue;
        const float v = acc[i][j][r];
        if constexpr (EPI == EPI_PATCH) {
          const int pb = m / 196, pp = m - pb * 196;
          const float val = v + bias[n] + pos[(size_t)(pp + 1) * 768 + n];
          ((float*)out0)[(size_t)(m + pb + 1) * 768 + n] = val;
        } else if constexpr (EPI == EPI_QKV) {
          ((bf16_t*)out0)[(size_t)m * 1536 + n] = (bf16_t)v;
        } else if constexpr (EPI == EPI_BIAS_RES) {
          float* hp = (float*)out0 + (size_t)m * 768 + n;
          *hp += v + bias[n];
        } else if constexpr (EPI == EPI_HEAD) {
          if (n < 1000)
            ((float*)out0)[(size_t)m * 1000 + n] = v + bias[n];
        } else {  // EPI_GELU
          ((bf16_t*)out0)[(size_t)m * (size_t)ldo + n] = (bf16_t)gelu_fast(v + bias[n]);
        }
      }
    }
  }
}

// ---------------- attention ----------------
// qk: [M_PAD][1536] bf16 (q cols 0..767 = h*64+d, k cols 768..1535)
// vt: [768][64][TPADV] bf16  (per (b*12+h): V^T, row d, col t; t>=197 zeroed once)
// attno: [M_PAD][768] bf16
__global__ __launch_bounds__(256, 2)
void attn_kernel(const bf16_t* __restrict__ qk, const bf16_t* __restrict__ vt,
                 bf16_t* __restrict__ attno) {
  __shared__ bf16_t Kl[224 * 72];
  __shared__ bf16_t Pl[4][16 * 232];
  const int bh = blockIdx.x;
  const int b = bh / 12, hh = bh % 12;
  const int tid = threadIdx.x, wv = tid >> 6, ln = tid & 63;
  const int tl = ln & 15, kg = ln >> 4;

  for (int idx = tid; idx < 224 * 8; idx += 256) {
    const int s = idx >> 3, c = idx & 7;
    bf16x8 val;
    if (s < 197) {
      val = *(const bf16x8*)(qk + (size_t)(b * 197 + s) * 1536 + 768 + hh * 64 + c * 8);
    } else {
#pragma unroll
      for (int j2 = 0; j2 < 8; ++j2) val[j2] = (bf16_t)0.f;
    }
    *(bf16x8*)&Kl[s * 72 + c * 8] = val;
  }
  __syncthreads();

  for (int qt = wv; qt < 13; qt += 4) {
    const size_t qoff = (size_t)(b * 197 + qt * 16 + tl) * 1536 + hh * 64 + kg * 8;
    const bf16x8 aq0 = *(const bf16x8*)(qk + qoff);
    const bf16x8 aq1 = *(const bf16x8*)(qk + qoff + 32);
    f32x4 sc[13];
#pragma unroll
    for (int st = 0; st < 13; ++st) {
      const bf16x8 bk0 = *(const bf16x8*)&Kl[(st * 16 + tl) * 72 + kg * 8];
      const bf16x8 bk1 = *(const bf16x8*)&Kl[(st * 16 + tl) * 72 + 32 + kg * 8];
      f32x4 z = {0.f, 0.f, 0.f, 0.f};
      z = __builtin_amdgcn_mfma_f32_16x16x32_bf16(aq0, bk0, z, 0, 0, 0);
      z = __builtin_amdgcn_mfma_f32_16x16x32_bf16(aq1, bk1, z, 0, 0, 0);
      sc[st] = z;
    }
#pragma unroll
    for (int st = 0; st < 13; ++st)
#pragma unroll
      for (int r = 0; r < 4; ++r) sc[st][r] *= 0.125f;  // HS^-0.5

    float inv[4];
#pragma unroll
    for (int r = 0; r < 4; ++r) {
      float sum = 0.f;
#pragma unroll
      for (int st = 0; st < 13; ++st)
        if (st * 16 + tl < 197) sum += sc[st][r];
      sum = rowred16(sum);
      const float mean = sum * (1.f / 197.f);
      float ss = 0.f;
#pragma unroll
      for (int st = 0; st < 13; ++st)
        if (st * 16 + tl < 197) { const float cc = sc[st][r] - mean; ss += cc * cc; }
      ss = rowred16(ss);
      const float rstd = rsqrtf(ss * (1.f / 197.f) + 1e-5f);
      float ps = 0.f;
#pragma unroll
      for (int st = 0; st < 13; ++st) {
        const int s = st * 16 + tl;
        float p = 0.f;
        if (s < 197) p = __expf((sc[st][r] - mean) * rstd);
        ps += p;
        Pl[wv][(kg * 4 + r) * 232 + st * 16 + tl] = (bf16_t)p;
      }
      ps = rowred16(ps);
      inv[r] = 1.f / ps;
      Pl[wv][(kg * 4 + r) * 232 + 208 + tl] = (bf16_t)0.f;
      if (tl < 8) Pl[wv][(kg * 4 + r) * 232 + 224 + tl] = (bf16_t)0.f;
    }

    f32x4 oa[4];
#pragma unroll
    for (int nf = 0; nf < 4; ++nf) {
      oa[nf][0] = 0.f; oa[nf][1] = 0.f; oa[nf][2] = 0.f; oa[nf][3] = 0.f;
    }
#pragma unroll
    for (int kk = 0; kk < 7; ++kk) {
      const bf16x8 pa = *(const bf16x8*)&Pl[wv][tl * 232 + kk * 32 + kg * 8];
#pragma unroll
      for (int nf = 0; nf < 4; ++nf) {
        const bf16x8 vb = *(const bf16x8*)(vt + ((size_t)bh * 64 + nf * 16 + tl) * TPADV + kk * 32 + kg * 8);
        oa[nf] = __builtin_amdgcn_mfma_f32_16x16x32_bf16(pa, vb, oa[nf], 0, 0, 0);
      }
    }
#pragma unroll
    for (int nf = 0; nf < 4; ++nf)
#pragma unroll
      for (int r = 0; r < 4; ++r) {
        const int t = qt * 16 + kg * 4 + r;
        if (t < 197)
          attno[(size_t)(b * 197 + t) * 768 + hh * 64 + nf * 16 + tl] =
              (bf16_t)(oa[nf][r] * inv[r]);
      }
  }
}

// ---------------- launch ----------------

extern "C" void kernel_launch(void* const* d_in, const int* in_sizes, int n_in,
                              void* d_out, int out_size, void* d_ws, size_t ws_size,
                              hipStream_t stream) {
  (void)in_sizes; (void)n_in; (void)out_size; (void)ws_size;
  const float* x      = (const float*)d_in[0];
  const float* conv_w = (const float*)d_in[1];
  const float* conv_b = (const float*)d_in[2];
  const float* cls_t  = (const float*)d_in[3];
  const float* pos    = (const float*)d_in[4];
  const float* Wq     = (const float*)d_in[5];
  const float* Wk     = (const float*)d_in[6];
  const float* Wv     = (const float*)d_in[7];
  const float* proj_w = (const float*)d_in[8];
  const float* proj_b = (const float*)d_in[9];
  const float* ln1_g  = (const float*)d_in[10];
  const float* ln1_b  = (const float*)d_in[11];
  const float* ln2_g  = (const float*)d_in[12];
  const float* ln2_b  = (const float*)d_in[13];
  const float* ff1_w  = (const float*)d_in[14];
  const float* ff1_b  = (const float*)d_in[15];
  const float* ff2_w  = (const float*)d_in[16];
  const float* ff2_b  = (const float*)d_in[17];
  const float* lnf_g  = (const float*)d_in[18];
  const float* lnf_b  = (const float*)d_in[19];
  const float* head_w = (const float*)d_in[20];
  const float* head_b = (const float*)d_in[21];
  float* out = (float*)d_out;

  char* w = (char*)d_ws;
  size_t off = 0;
  auto take = [&](size_t bytes) {
    char* p = w + off;
    off = (off + bytes + 255) & ~(size_t)255;
    return p;
  };
  bf16_t* Wc_t    = (bf16_t*)take((size_t)768 * 768 * 2);
  bf16_t* Wqkv_t  = (bf16_t*)take((size_t)12 * 2304 * 768 * 2);
  bf16_t* Wproj_t = (bf16_t*)take((size_t)12 * 768 * 768 * 2);
  bf16_t* Wff1_t  = (bf16_t*)take((size_t)12 * 3072 * 768 * 2);
  bf16_t* Wff2_t  = (bf16_t*)take((size_t)12 * 768 * 3072 * 2);
  bf16_t* Wht     = (bf16_t*)take((size_t)1024 * 768 * 2);
  float*  hbuf    = (float*)take((size_t)M_PAD * 768 * 4);
  bf16_t* xn      = (bf16_t*)take((size_t)M_PAD * 768 * 2);
  bf16_t* qkb     = (bf16_t*)take((size_t)M_PAD * 1536 * 2);
  bf16_t* vtb     = (bf16_t*)take((size_t)768 * 64 * TPADV * 2);
  bf16_t* attno   = (bf16_t*)take((size_t)M_PAD * 768 * 2);
  bf16_t* ffa     = (bf16_t*)take((size_t)M_PAD * 3072 * 2);
  bf16_t* xcls    = (bf16_t*)take((size_t)256 * 768 * 2);

  const dim3 blk256(256);
  const dim3 tb(32, 8);

  // weight conversion (fp32 -> bf16, [N][K] transposed layouts)
  tconv_kernel<<<dim3(24, 24, 12), tb, 0, stream>>>(proj_w, Wproj_t, 768, 768);
  tconv_kernel<<<dim3(96, 24, 12), tb, 0, stream>>>(ff1_w, Wff1_t, 768, 3072);
  tconv_kernel<<<dim3(24, 96, 12), tb, 0, stream>>>(ff2_w, Wff2_t, 3072, 768);
  qkvconv_kernel<<<dim3(24, 2, 432), tb, 0, stream>>>(Wq, Wk, Wv, Wqkv_t);
  headwconv_kernel<<<dim3(32, 24), tb, 0, stream>>>(head_w, Wht);
  cast_kernel<<<dim3(576), blk256, 0, stream>>>(conv_w, Wc_t, 147456);
  zerovt_kernel<<<dim3(2048), blk256, 0, stream>>>(vtb, 768 * 64 * TPADV / 8);

  // patch embed
  patch_kernel<<<dim3(2352), blk256, 0, stream>>>(x, xn);
  cls_kernel<<<dim3(64), blk256, 0, stream>>>(cls_t, pos, hbuf);
  gemm128<EPI_PATCH><<<dim3(6 * 98), blk256, 0, stream>>>(
      xn, Wc_t, 12544, 768, 6, (void*)hbuf, conv_b, pos, (bf16_t*)nullptr, 768);

  for (int i = 0; i < 12; ++i) {
    ln_kernel<<<dim3(3152), blk256, 0, stream>>>(hbuf, ln1_g + i * 768, ln1_b + i * 768, xn, M_TOK);
    // QKV: q,k -> qkb coalesced; V -> vtb via fused in-LDS transpose
    gemm128<EPI_QKV><<<dim3(18 * 99), blk256, 0, stream>>>(
        xn, Wqkv_t + (size_t)i * 2304 * 768, M_TOK, 768, 18, (void*)qkb,
        (const float*)nullptr, (const float*)nullptr, vtb, 1536);
    attn_kernel<<<dim3(768), blk256, 0, stream>>>(qkb, vtb, attno);
    gemm128<EPI_BIAS_RES><<<dim3(6 * 99), blk256, 0, stream>>>(
        attno, Wproj_t + (size_t)i * 768 * 768, M_TOK, 768, 6, (void*)hbuf,
        proj_b + i * 768, (const float*)nullptr, (bf16_t*)nullptr, 768);
    ln_kernel<<<dim3(3152), blk256, 0, stream>>>(hbuf, ln2_g + i * 768, ln2_b + i * 768, xn, M_TOK);
    gemm128<EPI_GELU><<<dim3(24 * 99), blk256, 0, stream>>>(
        xn, Wff1_t + (size_t)i * 768 * 3072, M_TOK, 768, 24, (void*)ffa,
        ff1_b + i * 3072, (const float*)nullptr, (bf16_t*)nullptr, 3072);
    gemm128<EPI_BIAS_RES><<<dim3(6 * 99), blk256, 0, stream>>>(
        ffa, Wff2_t + (size_t)i * 3072 * 768, M_TOK, 3072, 6, (void*)hbuf,
        ff2_b + i * 768, (const float*)nullptr, (bf16_t*)nullptr, 768);
  }

  lnf_cls_kernel<<<dim3(64), blk256, 0, stream>>>(hbuf, lnf_g, lnf_b, xcls);
  gemm128<EPI_HEAD><<<dim3(16), blk256, 0, stream>>>(
      xcls, Wht, 64, 768, 8, (void*)out, head_b, (const float*)nullptr,
      (bf16_t*)nullptr, 1000);
}